// Round 7
// baseline (135.041 us; speedup 1.0000x reference)
//
#include <hip/hip_runtime.h>
#include <stdint.h>

// ---------------------------------------------------------------------------
// AudioVisualModel fused loss on MI355X — R6: fp8 + 8-phase-lite schedule.
// B=16, Na=128, T=10, Nv=196, D=256.
// prep:  normalize (f32) -> fp8 e4m3. Audio linear [2048][256B]. Visual padded
//        per-t to 256 rows (2560/panel), 8B-unit swizzle u^(row&31).
// main:  1024 blocks = (x2: 64 audio rows, y, t-half). 4 waves = 2 aw x 2 vw.
//        af[16] in regs. Visual chunks 64 rows (16KB) in a 3-buffer ring,
//        2-deep prefetch via global_load_lds; ONE counted s_waitcnt vmcnt(4)
//        per chunk (never 0 in-loop). Each chunk = 2 phases of
//        {ds_read 8xb64 -> s_barrier -> lgkmcnt(0) -> sched_barrier ->
//         setprio(1) 8x MFMA setprio(0)}. Per-(col,t) max via LDS atomicMax.
// final: 16x16 InfoNCE + reg terms.
// ---------------------------------------------------------------------------

typedef float f32x16 __attribute__((ext_vector_type(16)));

#define WS_A_OFF  ((size_t)0)                          // 2048 x 256B = 512KB
#define WS_V_OFF  ((size_t)(1u<<20))                   // 16 x 2560 x 256B = 10.5MB
#define WS_CP_OFF (WS_V_OFF + (size_t)16*2560*256)     // clip [1024] + nn [1024]

#define NINF (-3.4e38f)

__device__ __forceinline__ int fenc(float f) {
    int i = __float_as_int(f);
    return i >= 0 ? i : (i ^ 0x7fffffff);
}
__device__ __forceinline__ float fdec(int i) {
    return __int_as_float(i >= 0 ? i : (i ^ 0x7fffffff));
}
__device__ __forceinline__ void gld_lds16(const char* g, char* l) {
    __builtin_amdgcn_global_load_lds(
        (const __attribute__((address_space(1))) void*)g,
        (__attribute__((address_space(3))) void*)l, 16, 0, 0);
}

// ---------------------------------------------------------------------------
// prep: one wave = 2 rows, 32 lanes/row, 8 f32 -> 8 fp8 per lane.
// rows [0,2048): audio (linear). [2048, 2048+40960): visual (padded+swizzled).
__global__ __launch_bounds__(256) void prep_kernel(const float* __restrict__ audio,
                                                   const float* __restrict__ visual,
                                                   char* __restrict__ ws)
{
    const int wave = blockIdx.x * 4 + (threadIdx.x >> 6);
    const int lane = threadIdx.x & 63;
    const int half = lane >> 5;
    const int sub  = lane & 31;
    const int row  = wave * 2 + half;          // [0, 43008)

    float f[8];
    #pragma unroll
    for (int i = 0; i < 8; ++i) f[i] = 0.f;
    size_t dst;
    if (row < 2048) {
        const float* s = audio + (size_t)row * 256 + sub * 8;
        *(float4*)(f)     = *(const float4*)(s);
        *(float4*)(f + 4) = *(const float4*)(s + 4);
        dst = WS_A_OFF + (size_t)row * 256 + sub * 8;
    } else {
        const int vr  = row - 2048;            // [0, 40960)
        const int y   = vr / 2560;
        const int rem = vr - y * 2560;
        const int t   = rem >> 8;
        const int vv  = rem & 255;
        if (vv < 196) {
            const float* s = visual + (size_t)((y*10 + t)*196 + vv) * 256 + sub * 8;
            *(float4*)(f)     = *(const float4*)(s);
            *(float4*)(f + 4) = *(const float4*)(s + 4);
        }
        dst = WS_V_OFF + (size_t)vr * 256 + (size_t)((sub ^ (vr & 31)) << 3);
    }

    float ss = 0.f;
    #pragma unroll
    for (int i = 0; i < 8; ++i) ss += f[i] * f[i];
    #pragma unroll
    for (int m = 1; m < 32; m <<= 1) ss += __shfl_xor(ss, m);   // within 32-lane half
    const float sc = 1.0f / fmaxf(sqrtf(ss), 1e-12f);           // zero row -> 0

    int w0 = __builtin_amdgcn_cvt_pk_fp8_f32(f[0]*sc, f[1]*sc, 0, false);
    w0     = __builtin_amdgcn_cvt_pk_fp8_f32(f[2]*sc, f[3]*sc, w0, true);
    int w1 = __builtin_amdgcn_cvt_pk_fp8_f32(f[4]*sc, f[5]*sc, 0, false);
    w1     = __builtin_amdgcn_cvt_pk_fp8_f32(f[6]*sc, f[7]*sc, w1, true);
    *(uint2*)(ws + dst) = make_uint2((unsigned)w0, (unsigned)w1);
}

// ---------------------------------------------------------------------------
#define STAGE(c_, buf_) do {                                          \
    const char* s_ = vbase + (size_t)(c_) * 16384 + tid * 16;         \
    char* d_ = &smem[buf_][0] + tid * 16;                             \
    gld_lds16(s_,         d_);         gld_lds16(s_ +  4096, d_ +  4096); \
    gld_lds16(s_ +  8192, d_ +  8192); gld_lds16(s_ + 12288, d_ + 12288); \
} while (0)

__global__ __launch_bounds__(256, 3) void main_kernel(char* __restrict__ ws)
{
    __shared__ __align__(16) char smem[3][16384];    // 3-buffer ring
    __shared__ int part[320];                        // [64 audio cols][5 t]
    __shared__ float red[8];

    const int tid  = threadIdx.x;
    const int lane = tid & 63;
    const int wid  = tid >> 6;
    const int aw   = wid & 1;            // audio strip (32 rows)
    const int vw   = wid >> 1;           // visual frag slot in chunk (32 rows)
    const int l31  = lane & 31;
    const int hi   = lane >> 5;

    const int b = blockIdx.x;
    const int xcd = b & 7, s = b >> 3;           // s in [0,128)
    const int y  = xcd * 2 + (s >> 6);           // each XCD: 2 y-panels (L2)
    const int x2 = (s & 63) >> 1;                // 64-row audio group [0,32)
    const int h  = s & 1;                        // t-half

    for (int i = tid; i < 320; i += 256) part[i] = (int)0x80000000;

    // audio fragments: 32 rows x K=256 -> af[16]
    uint64_t af[16];
    {
        const char* ab = ws + WS_A_OFF + (size_t)(x2*64 + aw*32 + l31) * 256 + hi*8;
        #pragma unroll
        for (int k = 0; k < 16; ++k)
            af[k] = *(const uint64_t*)(ab + k*16);
    }
    asm volatile("s_waitcnt vmcnt(0)" ::: "memory");   // af drained

    const char* vbase = ws + WS_V_OFF + ((size_t)y * 2560 + (size_t)h * 1280) * 256;

    float nn = 0.f, rmax = NINF;

    STAGE(0, 0);                                 // prologue: 2-deep prefetch
    STAGE(1, 1);
    asm volatile("s_waitcnt vmcnt(4) lgkmcnt(0)" ::: "memory");  // stage0 landed + part init
    __builtin_amdgcn_s_barrier();

    int bc = 0;                                  // ring buffer holding chunk c
    for (int c = 0; c < 20; ++c) {
        const int bs = (bc >= 1) ? bc - 1 : 2;   // (bc+2)%3
        if (c + 2 < 20) STAGE(c + 2, bs);        // 8 loads in flight (c+1, c+2)

        const int f  = 2*c + vw;                 // frag in [0,40)
        const int ft = f & 7;
        const bool ok = (ft != 7);               // ft==7: all-pad frag, skip compute
        const char* bb = &smem[bc][0] + (vw*32 + l31) * 256;

        f32x16 acc = {};
        uint64_t vfa[8];

        // ---- phase A: ds_read k=0..7 || (STAGE above) -> bar -> MFMA ----
        if (ok) {
            #pragma unroll
            for (int k = 0; k < 8; ++k)
                vfa[k] = *(const uint64_t*)(bb + (((k*2 + hi) ^ l31) << 3));
        }
        __builtin_amdgcn_s_barrier();
        asm volatile("s_waitcnt lgkmcnt(0)" ::: "memory");
        __builtin_amdgcn_sched_barrier(0);
        __builtin_amdgcn_s_setprio(1);
        if (ok) {
            #pragma unroll
            for (int k = 0; k < 8; ++k)
                acc = __builtin_amdgcn_mfma_f32_32x32x16_fp8_fp8(
                    (long)vfa[k], (long)af[k], acc, 0, 0, 0);
        }
        __builtin_amdgcn_s_setprio(0);
        __builtin_amdgcn_s_barrier();

        // ---- phase B: ds_read k=8..15 -> bar -> MFMA ----
        if (ok) {
            #pragma unroll
            for (int k = 0; k < 8; ++k)
                vfa[k] = *(const uint64_t*)(bb + ((((k + 8)*2 + hi) ^ l31) << 3));
        }
        __builtin_amdgcn_s_barrier();
        asm volatile("s_waitcnt lgkmcnt(0)" ::: "memory");
        __builtin_amdgcn_sched_barrier(0);
        __builtin_amdgcn_s_setprio(1);
        if (ok) {
            #pragma unroll
            for (int k = 0; k < 8; ++k)
                acc = __builtin_amdgcn_mfma_f32_32x32x16_fp8_fp8(
                    (long)vfa[k], (long)af[k + 8], acc, 0, 0, 0);
        }
        __builtin_amdgcn_s_setprio(0);

        // ---- epilogue VALU (overlaps other blocks' phases) ----
        if (ok) {
            #pragma unroll
            for (int i = 0; i < 16; ++i) {
                const float g = fminf(acc[i], 0.f);   // pad rows give exact 0
                nn = fmaf(g, g, nn);
            }
            float m;
            if (ft == 6) {   // valid visual rows 0-3 -> regs 0-3 at hi==0
                m = fmaxf(fmaxf(acc[0], acc[1]), fmaxf(acc[2], acc[3]));
                if (hi) m = NINF;
            } else {
                float a0 = fmaxf(fmaxf(acc[0], acc[1]),   fmaxf(acc[2], acc[3]));
                float a1 = fmaxf(fmaxf(acc[4], acc[5]),   fmaxf(acc[6], acc[7]));
                float a2 = fmaxf(fmaxf(acc[8], acc[9]),   fmaxf(acc[10], acc[11]));
                float a3 = fmaxf(fmaxf(acc[12], acc[13]), fmaxf(acc[14], acc[15]));
                m = fmaxf(fmaxf(a0, a1), fmaxf(a2, a3));
            }
            rmax = fmaxf(rmax, m);
        }
        if ((c & 3) == 3) {              // end of t (4 chunks = 8 frags)
            const int tl = c >> 2;       // local t in [0,5)
            float v = fmaxf(rmax, __shfl_xor(rmax, 32));
            if (hi == 0)
                atomicMax(&part[(aw*32 + l31) * 5 + tl], fenc(v));
            rmax = NINF;
        }

        // ---- chunk end: counted vmcnt (chunk c+1 landed), never 0 in-loop ----
        if (c < 18) asm volatile("s_waitcnt vmcnt(4)" ::: "memory");
        else        asm volatile("s_waitcnt vmcnt(0)" ::: "memory");
        __builtin_amdgcn_s_barrier();
        bc = (bc + 1 == 3) ? 0 : bc + 1;
    }

    __syncthreads();

    float sum = 0.f;
    for (int i = tid; i < 320; i += 256) sum += fdec(part[i]);
    #pragma unroll
    for (int m = 1; m < 64; m <<= 1) {
        sum += __shfl_xor(sum, m);
        nn  += __shfl_xor(nn, m);
    }
    if (lane == 0) { red[wid] = sum; red[4 + wid] = nn; }
    __syncthreads();
    if (tid == 0) {
        float S = 0.f, N = 0.f;
        #pragma unroll
        for (int w = 0; w < 4; ++w) { S += red[w]; N += red[4 + w]; }
        float* cp = (float*)(ws + WS_CP_OFF);
        const int idx = (x2*16 + y)*2 + h;       // [0,1024)
        cp[idx]        = S;
        cp[1024 + idx] = N;
    }
}

// ---------------------------------------------------------------------------
// final: 16x16 InfoNCE + regularizers -> 3 scalars
__global__ void final_kernel(const char* __restrict__ ws,
                             const float* __restrict__ temp,
                             float* __restrict__ out)
{
    __shared__ float cs[16][17];
    __shared__ float nnred[256];
    __shared__ float lse_r[16], lse_c[16];
    const int tid = threadIdx.x;
    const float T = temp[0];
    const float* cp = (const float*)(ws + WS_CP_OFF);
    const int x = tid >> 4, yy = tid & 15;
    float sclip = 0.f;
    #pragma unroll
    for (int a = 0; a < 2; ++a)
        #pragma unroll
        for (int hh = 0; hh < 2; ++hh)
            sclip += cp[(((2*x + a)*16 + yy)*2) + hh];
    cs[x][yy] = sclip / (1280.0f * T);
    float n = 0.f;
    #pragma unroll
    for (int j = 0; j < 4; ++j) n += cp[1024 + tid + j*256];
    nnred[tid] = n;
    __syncthreads();
    for (int s = 128; s > 0; s >>= 1) {
        if (tid < s) nnred[tid] += nnred[tid + s];
        __syncthreads();
    }
    if (tid < 16) {
        float m = NINF;
        for (int j = 0; j < 16; ++j) m = fmaxf(m, cs[tid][j]);
        float s = 0.f;
        for (int j = 0; j < 16; ++j) s += expf(cs[tid][j] - m);
        lse_r[tid] = m + logf(s);
    } else if (tid < 32) {
        const int c = tid - 16;
        float m = NINF;
        for (int j = 0; j < 16; ++j) m = fmaxf(m, cs[j][c]);
        float s = 0.f;
        for (int j = 0; j < 16; ++j) s += expf(cs[j][c] - m);
        lse_c[c] = m + logf(s);
    }
    __syncthreads();
    if (tid == 0) {
        float acc = 0.f;
        for (int i = 0; i < 16; ++i)
            acc += (lse_r[i] - cs[i][i]) + (lse_c[i] - cs[i][i]);
        const float contrastive = 0.5f * acc * (1.0f / 16.0f);
        const float l_nonneg = nnred[0] / (64225280.0f * T * T);
        const float lt = logf(T);
        float tl = fmaxf(-lt, 0.f); tl = tl * tl; tl = tl * tl;
        float th = fmaxf(lt - 1.0986122886681098f, 0.f); th = th * th; th = th * th;
        const float reg = l_nonneg + tl + th;
        out[0] = contrastive + 0.3f * reg;
        out[1] = contrastive;
        out[2] = reg;
    }
}

// ---------------------------------------------------------------------------
extern "C" void kernel_launch(void* const* d_in, const int* in_sizes, int n_in,
                              void* d_out, int out_size, void* d_ws, size_t ws_size,
                              hipStream_t stream)
{
    const float* audio  = (const float*)d_in[0];
    const float* visual = (const float*)d_in[1];
    const float* temp   = (const float*)d_in[2];
    char* ws = (char*)d_ws;

    prep_kernel<<<5376, 256, 0, stream>>>(audio, visual, ws);   // 43008 rows / 2 per wave
    main_kernel<<<1024, 256, 0, stream>>>(ws);                  // (x2, y, t-half)
    final_kernel<<<1, 256, 0, stream>>>(ws, temp, (float*)d_out);
}

// Round 8
// 112.409 us; speedup vs baseline: 1.2013x; 1.2013x over previous
//
#include <hip/hip_runtime.h>
#include <stdint.h>

// ---------------------------------------------------------------------------
// AudioVisualModel fused loss on MI355X — R8: R5 skeleton + MX-scaled fp8 K=64.
// B=16, Na=128, T=10, Nv=196, D=256.
// prep:  normalize (f32) -> fp8 e4m3. Audio linear [2048][256B]. Visual padded
//        per-t to 256 rows (2560/panel), 8B-unit swizzle u^(row&31).
// main:  1024 blocks = (x2: 64 audio rows, y, t-half). 4 waves = 2 aw x 2 vw.
//        af 4x i32x8 in regs. Visual chunks 64 rows (16KB) double-buffered via
//        global_load_lds; 2 barriers/chunk, counted s_waitcnt vmcnt(4).
//        Core: 4x mfma_scale_f32_32x32x64_f8f6f4 (unit scales) per frag.
// final: 16x16 InfoNCE + reg terms.
// ---------------------------------------------------------------------------

typedef float f32x16 __attribute__((ext_vector_type(16)));
typedef int   i32x8  __attribute__((ext_vector_type(8)));

#define WS_A_OFF  ((size_t)0)                          // 2048 x 256B = 512KB
#define WS_V_OFF  ((size_t)(1u<<20))                   // 16 x 2560 x 256B = 10.5MB
#define WS_CP_OFF (WS_V_OFF + (size_t)16*2560*256)     // clip [1024] + nn [1024]

#define NINF (-3.4e38f)
#define SCL1 0x7F7F7F7F                                // E8M0 127 = 2^0 per byte

__device__ __forceinline__ int fenc(float f) {
    int i = __float_as_int(f);
    return i >= 0 ? i : (i ^ 0x7fffffff);
}
__device__ __forceinline__ float fdec(int i) {
    return __int_as_float(i >= 0 ? i : (i ^ 0x7fffffff));
}
__device__ __forceinline__ void gld_lds16(const char* g, char* l) {
    __builtin_amdgcn_global_load_lds(
        (const __attribute__((address_space(1))) void*)g,
        (__attribute__((address_space(3))) void*)l, 16, 0, 0);
}

// ---------------------------------------------------------------------------
// prep: one wave = 2 rows, 32 lanes/row, 8 f32 -> 8 fp8 per lane.
// rows [0,2048): audio (linear). [2048, 2048+40960): visual (padded+swizzled).
__global__ __launch_bounds__(256) void prep_kernel(const float* __restrict__ audio,
                                                   const float* __restrict__ visual,
                                                   char* __restrict__ ws)
{
    const int wave = blockIdx.x * 4 + (threadIdx.x >> 6);
    const int lane = threadIdx.x & 63;
    const int half = lane >> 5;
    const int sub  = lane & 31;
    const int row  = wave * 2 + half;          // [0, 43008)

    float f[8];
    #pragma unroll
    for (int i = 0; i < 8; ++i) f[i] = 0.f;
    size_t dst;
    if (row < 2048) {
        const float* s = audio + (size_t)row * 256 + sub * 8;
        *(float4*)(f)     = *(const float4*)(s);
        *(float4*)(f + 4) = *(const float4*)(s + 4);
        dst = WS_A_OFF + (size_t)row * 256 + sub * 8;
    } else {
        const int vr  = row - 2048;            // [0, 40960)
        const int y   = vr / 2560;
        const int rem = vr - y * 2560;
        const int t   = rem >> 8;
        const int vv  = rem & 255;
        if (vv < 196) {
            const float* s = visual + (size_t)((y*10 + t)*196 + vv) * 256 + sub * 8;
            *(float4*)(f)     = *(const float4*)(s);
            *(float4*)(f + 4) = *(const float4*)(s + 4);
        }
        dst = WS_V_OFF + (size_t)vr * 256 + (size_t)((sub ^ (vr & 31)) << 3);
    }

    float ss = 0.f;
    #pragma unroll
    for (int i = 0; i < 8; ++i) ss += f[i] * f[i];
    #pragma unroll
    for (int m = 1; m < 32; m <<= 1) ss += __shfl_xor(ss, m);   // within 32-lane half
    const float sc = 1.0f / fmaxf(sqrtf(ss), 1e-12f);           // zero row -> 0

    int w0 = __builtin_amdgcn_cvt_pk_fp8_f32(f[0]*sc, f[1]*sc, 0, false);
    w0     = __builtin_amdgcn_cvt_pk_fp8_f32(f[2]*sc, f[3]*sc, w0, true);
    int w1 = __builtin_amdgcn_cvt_pk_fp8_f32(f[4]*sc, f[5]*sc, 0, false);
    w1     = __builtin_amdgcn_cvt_pk_fp8_f32(f[6]*sc, f[7]*sc, w1, true);
    *(uint2*)(ws + dst) = make_uint2((unsigned)w0, (unsigned)w1);
}

// ---------------------------------------------------------------------------
#define STAGE(c_, buf_) do {                                          \
    const char* s_ = vbase + (size_t)(c_) * 16384 + tid * 16;         \
    char* d_ = &smem[buf_][0] + tid * 16;                             \
    gld_lds16(s_,         d_);         gld_lds16(s_ +  4096, d_ +  4096); \
    gld_lds16(s_ +  8192, d_ +  8192); gld_lds16(s_ + 12288, d_ + 12288); \
} while (0)

__global__ __launch_bounds__(256, 4) void main_kernel(char* __restrict__ ws)
{
    __shared__ __align__(16) char smem[2][16384];
    __shared__ int part[320];                    // [64 audio cols][5 t]
    __shared__ float red[8];

    const int tid  = threadIdx.x;
    const int lane = tid & 63;
    const int wid  = tid >> 6;
    const int aw   = wid & 1;            // audio strip (32 rows)
    const int vw   = wid >> 1;           // visual frag slot in chunk (32 rows)
    const int l31  = lane & 31;
    const int hi   = lane >> 5;

    const int b = blockIdx.x;
    const int xcd = b & 7, s = b >> 3;           // s in [0,128)
    const int y  = xcd * 2 + (s >> 6);           // each XCD: 2 y-panels (L2)
    const int x2 = (s & 63) >> 1;                // 64-row audio group [0,32)
    const int h  = s & 1;                        // t-half

    for (int i = tid; i < 320; i += 256) part[i] = (int)0x80000000;

    // audio fragments: 32 rows x K=256 -> 4x i32x8 (32 VGPR).
    // B-operand layout (32x32x64): col = lane&31, k-chunk = 32*(lane>>5).
    i32x8 af[4];
    {
        const char* ab = ws + WS_A_OFF + (size_t)(x2*64 + aw*32 + l31) * 256 + hi*32;
        #pragma unroll
        for (int m = 0; m < 4; ++m) {
            const uint4 p = *(const uint4*)(ab + m*64);
            const uint4 q = *(const uint4*)(ab + m*64 + 16);
            af[m][0] = (int)p.x; af[m][1] = (int)p.y; af[m][2] = (int)p.z; af[m][3] = (int)p.w;
            af[m][4] = (int)q.x; af[m][5] = (int)q.y; af[m][6] = (int)q.z; af[m][7] = (int)q.w;
        }
    }
    asm volatile("s_waitcnt vmcnt(0)" ::: "memory");   // af drained
    __syncthreads();                                   // part init visible

    const char* vbase = ws + WS_V_OFF + ((size_t)y * 2560 + (size_t)h * 1280) * 256;

    float nn = 0.f, rmax = NINF;

    STAGE(0, 0);

    for (int c = 0; c < 20; ++c) {
        if (c < 19) {
            STAGE(c + 1, (c + 1) & 1);
            asm volatile("s_waitcnt vmcnt(4)" ::: "memory");   // stage(c) landed
        } else {
            asm volatile("s_waitcnt vmcnt(0)" ::: "memory");
        }
        __builtin_amdgcn_s_barrier();

        const int f  = 2*c + vw;                 // frag in [0,40)
        const int ft = f & 7;
        if (ft != 7) {                           // ft==7: all-pad frag, skip
            const char* bb = &smem[c & 1][0] + (vw*32 + l31) * 256;

            f32x16 acc = {};
            #pragma unroll
            for (int m = 0; m < 4; ++m) {
                // A-operand: row = lane&31 (visual), k-chunk = 32*hi within K=64.
                // 8B units swizzled by ^l31.
                const uint2 r0 = *(const uint2*)(bb + (((m*8 + hi*4 + 0) ^ l31) << 3));
                const uint2 r1 = *(const uint2*)(bb + (((m*8 + hi*4 + 1) ^ l31) << 3));
                const uint2 r2 = *(const uint2*)(bb + (((m*8 + hi*4 + 2) ^ l31) << 3));
                const uint2 r3 = *(const uint2*)(bb + (((m*8 + hi*4 + 3) ^ l31) << 3));
                i32x8 va;
                va[0] = (int)r0.x; va[1] = (int)r0.y; va[2] = (int)r1.x; va[3] = (int)r1.y;
                va[4] = (int)r2.x; va[5] = (int)r2.y; va[6] = (int)r3.x; va[7] = (int)r3.y;
                acc = __builtin_amdgcn_mfma_scale_f32_32x32x64_f8f6f4(
                    va, af[m], acc, 0 /*cbsz: fp8*/, 0 /*blgp: fp8*/,
                    0, SCL1, 0, SCL1);
            }

            // nonneg: pad rows are exact zeros -> contribute 0
            #pragma unroll
            for (int i = 0; i < 16; ++i) {
                const float g = fminf(acc[i], 0.f);
                nn = fmaf(g, g, nn);
            }
            float m;
            if (ft == 6) {   // valid visual rows 192-195 -> regs 0-3 at hi==0
                m = fmaxf(fmaxf(acc[0], acc[1]), fmaxf(acc[2], acc[3]));
                if (hi) m = NINF;
            } else {
                float a0 = fmaxf(fmaxf(acc[0], acc[1]),   fmaxf(acc[2], acc[3]));
                float a1 = fmaxf(fmaxf(acc[4], acc[5]),   fmaxf(acc[6], acc[7]));
                float a2 = fmaxf(fmaxf(acc[8], acc[9]),   fmaxf(acc[10], acc[11]));
                float a3 = fmaxf(fmaxf(acc[12], acc[13]), fmaxf(acc[14], acc[15]));
                m = fmaxf(fmaxf(a0, a1), fmaxf(a2, a3));
            }
            rmax = fmaxf(rmax, m);
        }

        if ((c & 3) == 3) {              // end of t (4 chunks = 8 frags)
            const int tl = c >> 2;       // local t in [0,5)
            float v = fmaxf(rmax, __shfl_xor(rmax, 32));
            if (hi == 0)
                atomicMax(&part[(aw*32 + l31) * 5 + tl], fenc(v));
            rmax = NINF;
        }
        asm volatile("" ::: "memory");
        __builtin_amdgcn_s_barrier();    // buf[cur] reads done before restage
    }

    __syncthreads();

    float sum = 0.f;
    for (int i = tid; i < 320; i += 256) sum += fdec(part[i]);
    #pragma unroll
    for (int m = 1; m < 64; m <<= 1) {
        sum += __shfl_xor(sum, m);
        nn  += __shfl_xor(nn, m);
    }
    if (lane == 0) { red[wid] = sum; red[4 + wid] = nn; }
    __syncthreads();
    if (tid == 0) {
        float S = 0.f, N = 0.f;
        #pragma unroll
        for (int w = 0; w < 4; ++w) { S += red[w]; N += red[4 + w]; }
        float* cp = (float*)(ws + WS_CP_OFF);
        const int idx = (x2*16 + y)*2 + h;       // [0,1024)
        cp[idx]        = S;
        cp[1024 + idx] = N;
    }
}

// ---------------------------------------------------------------------------
// final: 16x16 InfoNCE + regularizers -> 3 scalars
__global__ void final_kernel(const char* __restrict__ ws,
                             const float* __restrict__ temp,
                             float* __restrict__ out)
{
    __shared__ float cs[16][17];
    __shared__ float nnred[256];
    __shared__ float lse_r[16], lse_c[16];
    const int tid = threadIdx.x;
    const float T = temp[0];
    const float* cp = (const float*)(ws + WS_CP_OFF);
    const int x = tid >> 4, yy = tid & 15;
    float sclip = 0.f;
    #pragma unroll
    for (int a = 0; a < 2; ++a)
        #pragma unroll
        for (int hh = 0; hh < 2; ++hh)
            sclip += cp[(((2*x + a)*16 + yy)*2) + hh];
    cs[x][yy] = sclip / (1280.0f * T);
    float n = 0.f;
    #pragma unroll
    for (int j = 0; j < 4; ++j) n += cp[1024 + tid + j*256];
    nnred[tid] = n;
    __syncthreads();
    for (int s = 128; s > 0; s >>= 1) {
        if (tid < s) nnred[tid] += nnred[tid + s];
        __syncthreads();
    }
    if (tid < 16) {
        float m = NINF;
        for (int j = 0; j < 16; ++j) m = fmaxf(m, cs[tid][j]);
        float s = 0.f;
        for (int j = 0; j < 16; ++j) s += expf(cs[tid][j] - m);
        lse_r[tid] = m + logf(s);
    } else if (tid < 32) {
        const int c = tid - 16;
        float m = NINF;
        for (int j = 0; j < 16; ++j) m = fmaxf(m, cs[j][c]);
        float s = 0.f;
        for (int j = 0; j < 16; ++j) s += expf(cs[j][c] - m);
        lse_c[c] = m + logf(s);
    }
    __syncthreads();
    if (tid == 0) {
        float acc = 0.f;
        for (int i = 0; i < 16; ++i)
            acc += (lse_r[i] - cs[i][i]) + (lse_c[i] - cs[i][i]);
        const float contrastive = 0.5f * acc * (1.0f / 16.0f);
        const float l_nonneg = nnred[0] / (64225280.0f * T * T);
        const float lt = logf(T);
        float tl = fmaxf(-lt, 0.f); tl = tl * tl; tl = tl * tl;
        float th = fmaxf(lt - 1.0986122886681098f, 0.f); th = th * th; th = th * th;
        const float reg = l_nonneg + tl + th;
        out[0] = contrastive + 0.3f * reg;
        out[1] = contrastive;
        out[2] = reg;
    }
}

// ---------------------------------------------------------------------------
extern "C" void kernel_launch(void* const* d_in, const int* in_sizes, int n_in,
                              void* d_out, int out_size, void* d_ws, size_t ws_size,
                              hipStream_t stream)
{
    const float* audio  = (const float*)d_in[0];
    const float* visual = (const float*)d_in[1];
    const float* temp   = (const float*)d_in[2];
    char* ws = (char*)d_ws;

    prep_kernel<<<5376, 256, 0, stream>>>(audio, visual, ws);   // 43008 rows / 2 per wave
    main_kernel<<<1024, 256, 0, stream>>>(ws);                  // (x2, y, t-half)
    final_kernel<<<1, 256, 0, stream>>>(ws, temp, (float*)d_out);
}